// Round 1
// 568.675 us; speedup vs baseline: 1.1377x; 1.1377x over previous
//
#include <hip/hip_runtime.h>
#include <hip/hip_bf16.h>
#include <stdint.h>

#define TOKENS 8192
#define D_IN   2048
#define D_OUT  8192
#define BK     64
#define NT     (D_IN / BK)   // 32 K-tiles

typedef __attribute__((ext_vector_type(8))) short short8;
typedef __attribute__((ext_vector_type(4))) float floatx4;

// async global->LDS, 16B per lane. LDS dest is wave-uniform base + lane*16.
__device__ __forceinline__ void async_copy16(const void* g, void* l) {
    __builtin_amdgcn_global_load_lds((const __attribute__((address_space(1))) void*)g,
                                     (__attribute__((address_space(3))) void*)l,
                                     16, 0, 0);
}

// ---------------------------------------------------------------------------
// FWHT over last dim (2048) of x [8192,2048] fp32 -> bf16 x_h in workspace.
// (unchanged from previous verified version)
// ---------------------------------------------------------------------------
__device__ __forceinline__ void fwht8(float* e) {
#pragma unroll
    for (int s = 1; s < 8; s <<= 1) {
#pragma unroll
        for (int j = 0; j < 8; ++j) {
            if ((j & s) == 0) {
                float a = e[j], b = e[j | s];
                e[j]     = a + b;
                e[j | s] = a - b;
            }
        }
    }
}

__global__ __launch_bounds__(256) void fwht_kernel(const float* __restrict__ x,
                                                   __hip_bfloat16* __restrict__ xh) {
    __shared__ float row[D_IN];
    const int r = blockIdx.x;
    const int t = threadIdx.x;
    const float* xr = x + (size_t)r * D_IN;

    float e[8];
#pragma unroll
    for (int j = 0; j < 8; ++j) e[j] = xr[t + 256 * j];
    fwht8(e);
#pragma unroll
    for (int j = 0; j < 8; ++j) row[t + 256 * j] = e[j];
    __syncthreads();

    float f[8];
#pragma unroll
    for (int j = 0; j < 8; ++j) f[j] = row[8 * t + j];
    fwht8(f);
#pragma unroll
    for (int m = 1; m <= 16; m <<= 1) {
#pragma unroll
        for (int j = 0; j < 8; ++j) {
            float v = __shfl_xor(f[j], m, 64);
            f[j] = (t & m) ? (v - f[j]) : (f[j] + v);
        }
    }

    const float scale = 0.02209708691207961f;  // 1/sqrt(2048)
    __hip_bfloat16 ob[8];
#pragma unroll
    for (int j = 0; j < 8; ++j) ob[j] = __float2bfloat16(f[j] * scale);
    __hip_bfloat16* orow = xh + (size_t)r * D_IN + 8 * t;
    *reinterpret_cast<int4*>(orow) = *reinterpret_cast<int4*>(ob);
}

// ---------------------------------------------------------------------------
// Weight fp32 -> bf16 (exact: w values are fp8-e4m3 representable).
// ---------------------------------------------------------------------------
__global__ __launch_bounds__(256) void wconv_kernel(const float* __restrict__ w,
                                                    __hip_bfloat16* __restrict__ wb) {
    const size_t i = ((size_t)blockIdx.x * 256 + threadIdx.x) * 8;
    float4 a = *reinterpret_cast<const float4*>(w + i);
    float4 b = *reinterpret_cast<const float4*>(w + i + 4);
    __hip_bfloat16 ob[8];
    ob[0] = __float2bfloat16(a.x); ob[1] = __float2bfloat16(a.y);
    ob[2] = __float2bfloat16(a.z); ob[3] = __float2bfloat16(a.w);
    ob[4] = __float2bfloat16(b.x); ob[5] = __float2bfloat16(b.y);
    ob[6] = __float2bfloat16(b.z); ob[7] = __float2bfloat16(b.w);
    *reinterpret_cast<int4*>(wb + i) = *reinterpret_cast<int4*>(ob);
}

// ---------------------------------------------------------------------------
// GEMM: C[t,o] = sum_d A[t,d]*B[o,d] + bias[o].  A=x_h bf16, B=w bf16.
// 256x256 tile, BK=64, 512 thr (8 waves, 2x4), wave tile 128x64.
// 8-phase-style schedule (2 K-tiles per 8 phases), counted vmcnt(4),
// chunk-XOR LDS swizzle (conflict-free ds_read_b128), XCD block swizzle,
// setprio around MFMA clusters.  LDS: 2 dbuf x (A 32KB + B 32KB) = 128KB.
//
// LDS layout per buffer: row r (0..255), 16B chunk c (0..7):
//   byte = r*128 + (c ^ (r&7))*16        (bijective involution per row)
// Staging writes linearly (gload_lds), so the SOURCE chunk is pre-swizzled:
//   lane l covers dest row q*8+(l>>3), dest chunk l&7 -> src chunk (l&7)^(l>>3)
//
// Per K-tile kt (phases 0..3), buf = kt&1:
//  ph0: ds_read A m0-3 (8) + B n0-1 (4); stage B(kt+1,h0) -> buf^1
//  ph1: ds_read A m4-7 (8);              stage B(kt+1,h1) -> buf^1
//  ph2: ds_read B n2-3 (4);              stage A(kt+2,h0) -> buf  (A slots
//       freed after ph1: all A frags held in regs from ph0/ph1)
//  ph3: (no reads);                      stage A(kt+2,h1) -> buf
//       then s_waitcnt vmcnt(4) (allows A(kt+2) in flight, guarantees
//       B(kt+1) + everything older landed) -> next tile.
// Tail: vmcnt(0) when kt+2 >= NT (epilogue drain).  All barriers are raw
// s_barrier (no vmcnt drain at barriers - that was the m97 ceiling).
// ---------------------------------------------------------------------------
__global__ __launch_bounds__(512, 2) void gemm_kernel(const __hip_bfloat16* __restrict__ A,
                                                      const __hip_bfloat16* __restrict__ B,
                                                      const float* __restrict__ bias,
                                                      float* __restrict__ C) {
    extern __shared__ float4 smem_f4[];
    __hip_bfloat16* sA = (__hip_bfloat16*)smem_f4;           // [2][256][64]
    __hip_bfloat16* sB = sA + 2 * 16384;                     // [2][256][64]

    const int tid    = threadIdx.x;
    const int wave   = tid >> 6;
    const int lane   = tid & 63;
    const int lane16 = lane & 15;
    const int lgrp   = lane >> 4;

    // XCD-aware bijective swizzle: 1024 blocks, 8 XCDs -> each XCD gets a
    // contiguous run of 128 tiles (4 bm rows) for A-panel L2 reuse.
    const int bid = blockIdx.x;
    const int s   = (bid & 7) * 128 + (bid >> 3);
    const int bm  = s >> 5;   // 0..31
    const int bn  = s & 31;   // 0..31

    const int wm = wave >> 2; // 0..1
    const int wn = wave & 3;  // 0..3

    // ---- staging geometry (2 gload_lds per half-tile per thread) ----
    const int srow = lane >> 3;                 // 0..7
    const int scc8 = ((lane & 7) ^ srow) * 8;   // pre-swizzled source chunk
    const int r0   = wave * 16 + srow;          // instr-0 row within 128-row half
    const __hip_bfloat16* gAst = A + (size_t)(bm * 256) * D_IN + scc8;
    const __hip_bfloat16* gBst = B + (size_t)(bn * 256) * D_IN + scc8;

    auto stageA = [&](int kt, int h) {
        const __hip_bfloat16* g = gAst + (size_t)(h * 128 + r0) * D_IN + kt * BK;
        __hip_bfloat16* l = sA + (kt & 1) * 16384 + h * 8192 + wave * 1024;
        async_copy16(g, l);
        async_copy16(g + (size_t)8 * D_IN, l + 512);
    };
    auto stageB = [&](int kt, int h) {
        const __hip_bfloat16* g = gBst + (size_t)(h * 128 + r0) * D_IN + kt * BK;
        __hip_bfloat16* l = sB + (kt & 1) * 16384 + h * 8192 + wave * 1024;
        async_copy16(g, l);
        async_copy16(g + (size_t)8 * D_IN, l + 512);
    };

    // ---- ds_read fragment geometry (swizzled chunk, conflict-free) ----
    const int sw   = lane16 & 7;
    const int cK0  = ((0 + lgrp) ^ sw) * 8;   // kk=0 chunk elem offset
    const int cK1  = ((4 + lgrp) ^ sw) * 8;   // kk=1 chunk elem offset
    const int arow = wm * 128 + lane16;       // + m*16
    const int brow = wn * 64  + lane16;       // + n*16

    floatx4 acc[8][4];
#pragma unroll
    for (int m = 0; m < 8; ++m)
#pragma unroll
        for (int n = 0; n < 4; ++n) acc[m][n] = 0;

    // ---- prologue: A0(h0,h1) B0(h0,h1) A1(h0,h1); vmcnt(4) keeps A1 in flight
    stageA(0, 0); stageA(0, 1);
    stageB(0, 0); stageB(0, 1);
    stageA(1, 0); stageA(1, 1);
    asm volatile("s_waitcnt vmcnt(4)" ::: "memory");
    asm volatile("s_barrier" ::: "memory");

    short8 af[8][2];
    short8 bf[4][2];

#pragma unroll 2
    for (int kt = 0; kt < NT; ++kt) {
        const __hip_bfloat16* aB = sA + ((kt & 1) << 14);
        const __hip_bfloat16* bB = sB + ((kt & 1) << 14);

        // ======== phase 0: read A m0-3 + B n0-1; stage B(kt+1,h0) ========
#pragma unroll
        for (int m = 0; m < 4; ++m) {
            const __hip_bfloat16* p = aB + (arow + m * 16) * 64;
            af[m][0] = *reinterpret_cast<const short8*>(p + cK0);
            af[m][1] = *reinterpret_cast<const short8*>(p + cK1);
        }
#pragma unroll
        for (int n = 0; n < 2; ++n) {
            const __hip_bfloat16* p = bB + (brow + n * 16) * 64;
            bf[n][0] = *reinterpret_cast<const short8*>(p + cK0);
            bf[n][1] = *reinterpret_cast<const short8*>(p + cK1);
        }
        if (kt + 1 < NT) stageB(kt + 1, 0);
        asm volatile("s_barrier" ::: "memory");
        __builtin_amdgcn_s_setprio(1);
#pragma unroll
        for (int m = 0; m < 4; ++m)
#pragma unroll
            for (int n = 0; n < 2; ++n) {
                acc[m][n] = __builtin_amdgcn_mfma_f32_16x16x32_bf16(af[m][0], bf[n][0], acc[m][n], 0, 0, 0);
                acc[m][n] = __builtin_amdgcn_mfma_f32_16x16x32_bf16(af[m][1], bf[n][1], acc[m][n], 0, 0, 0);
            }
        __builtin_amdgcn_s_setprio(0);
        asm volatile("s_barrier" ::: "memory");

        // ======== phase 1: read A m4-7; stage B(kt+1,h1) ========
#pragma unroll
        for (int m = 4; m < 8; ++m) {
            const __hip_bfloat16* p = aB + (arow + m * 16) * 64;
            af[m][0] = *reinterpret_cast<const short8*>(p + cK0);
            af[m][1] = *reinterpret_cast<const short8*>(p + cK1);
        }
        if (kt + 1 < NT) stageB(kt + 1, 1);
        asm volatile("s_barrier" ::: "memory");
        __builtin_amdgcn_s_setprio(1);
#pragma unroll
        for (int m = 4; m < 8; ++m)
#pragma unroll
            for (int n = 0; n < 2; ++n) {
                acc[m][n] = __builtin_amdgcn_mfma_f32_16x16x32_bf16(af[m][0], bf[n][0], acc[m][n], 0, 0, 0);
                acc[m][n] = __builtin_amdgcn_mfma_f32_16x16x32_bf16(af[m][1], bf[n][1], acc[m][n], 0, 0, 0);
            }
        __builtin_amdgcn_s_setprio(0);
        asm volatile("s_barrier" ::: "memory");

        // ======== phase 2: read B n2-3; stage A(kt+2,h0) ========
#pragma unroll
        for (int n = 2; n < 4; ++n) {
            const __hip_bfloat16* p = bB + (brow + n * 16) * 64;
            bf[n][0] = *reinterpret_cast<const short8*>(p + cK0);
            bf[n][1] = *reinterpret_cast<const short8*>(p + cK1);
        }
        if (kt + 2 < NT) stageA(kt + 2, 0);
        asm volatile("s_barrier" ::: "memory");
        __builtin_amdgcn_s_setprio(1);
#pragma unroll
        for (int m = 0; m < 4; ++m)
#pragma unroll
            for (int n = 2; n < 4; ++n) {
                acc[m][n] = __builtin_amdgcn_mfma_f32_16x16x32_bf16(af[m][0], bf[n][0], acc[m][n], 0, 0, 0);
                acc[m][n] = __builtin_amdgcn_mfma_f32_16x16x32_bf16(af[m][1], bf[n][1], acc[m][n], 0, 0, 0);
            }
        __builtin_amdgcn_s_setprio(0);
        asm volatile("s_barrier" ::: "memory");

        // ======== phase 3: stage A(kt+2,h1); checkpoint vmcnt ========
        if (kt + 2 < NT) stageA(kt + 2, 1);
        asm volatile("s_barrier" ::: "memory");
        __builtin_amdgcn_s_setprio(1);
#pragma unroll
        for (int m = 4; m < 8; ++m)
#pragma unroll
            for (int n = 2; n < 4; ++n) {
                acc[m][n] = __builtin_amdgcn_mfma_f32_16x16x32_bf16(af[m][0], bf[n][0], acc[m][n], 0, 0, 0);
                acc[m][n] = __builtin_amdgcn_mfma_f32_16x16x32_bf16(af[m][1], bf[n][1], acc[m][n], 0, 0, 0);
            }
        __builtin_amdgcn_s_setprio(0);
        if (kt + 2 < NT) {
            asm volatile("s_waitcnt vmcnt(4)" ::: "memory");  // A(kt+2) may stay in flight
        } else {
            asm volatile("s_waitcnt vmcnt(0)" ::: "memory");  // tail drain
        }
        asm volatile("s_barrier" ::: "memory");
    }

    // ---- epilogue: C/D layout col=lane&15, row=lgrp*4+r ----
    float bv[4];
#pragma unroll
    for (int n = 0; n < 4; ++n) bv[n] = bias[bn * 256 + wn * 64 + n * 16 + lane16];

#pragma unroll
    for (int m = 0; m < 8; ++m) {
        const int rbase = bm * 256 + wm * 128 + m * 16 + lgrp * 4;
#pragma unroll
        for (int n = 0; n < 4; ++n) {
            const int col = bn * 256 + wn * 64 + n * 16 + lane16;
#pragma unroll
            for (int r = 0; r < 4; ++r) {
                C[(size_t)(rbase + r) * D_OUT + col] = acc[m][n][r] + bv[n];
            }
        }
    }
}

extern "C" void kernel_launch(void* const* d_in, const int* in_sizes, int n_in,
                              void* d_out, int out_size, void* d_ws, size_t ws_size,
                              hipStream_t stream) {
    const float* x    = (const float*)d_in[0];
    const float* w    = (const float*)d_in[1];
    const float* bias = (const float*)d_in[2];
    float* out = (float*)d_out;

    __hip_bfloat16* xh = (__hip_bfloat16*)d_ws;                      // 32 MB
    __hip_bfloat16* wb = xh + (size_t)TOKENS * D_IN;                 // 32 MB

    static bool attr_set = false;
    if (!attr_set) {
        (void)hipFuncSetAttribute((const void*)gemm_kernel,
                                  hipFuncAttributeMaxDynamicSharedMemorySize, 131072);
        attr_set = true;
    }

    fwht_kernel<<<TOKENS, 256, 0, stream>>>(x, xh);
    wconv_kernel<<<(D_OUT * D_IN / 8) / 256, 256, 0, stream>>>(w, wb);
    gemm_kernel<<<1024, 512, 131072, stream>>>(xh, wb, bias, out);
}